// Round 1
// baseline (360.068 us; speedup 1.0000x reference)
//
#include <hip/hip_runtime.h>
#include <stdint.h>

constexpr int B = 2, H = 256, W = 256, G = 96, C = 12, K = 128;
constexpr int HW = H * W;          // 65536
constexpr int G3 = G * G * G;      // 884736
constexpr float CENTER_THRESHOLD = 0.1f;
constexpr int NMSR = 3;            // (7-1)/2
constexpr int STUFF_AREA = 2048;
constexpr int LABEL_DIVISOR = 1000;
constexpr float VOXEL_SIZE = 0.0625f;
constexpr float TRUNCATION = 3.0f;
constexpr float TSDF_THRESH = 1.5f;
constexpr float DEPTH_MAX = 6.0f;
constexpr float HALF_EXT = 3.0f;   // G*VOXEL_SIZE/2

// output layout (floats)
constexpr size_t O_PAN2 = 0;
constexpr size_t O_PAN3 = 131072;
constexpr size_t O_GEOM = 1900544;
constexpr size_t O_CENT = 3670016;
constexpr size_t O_CLS  = 3670528;
constexpr size_t O_SCR  = 3670784;

// ws layout (bytes)
constexpr size_t WS_CY   = 256;
constexpr size_t WS_CX   = 1280;
constexpr size_t WS_SC   = 2304;
constexpr size_t WS_CL   = 3328;
constexpr size_t WS_SEM2 = 4352;
constexpr size_t WS_NMS  = 135424;
constexpr size_t WS_CV   = 266496;
constexpr size_t WS_CI   = 790784;
constexpr size_t WS_SEM3 = 1315072;

__global__ void k_pre2d(const float* __restrict__ sem2in,
                        const float* __restrict__ center2d,
                        uint8_t* __restrict__ semMap, uint8_t* __restrict__ nmsMask,
                        float* __restrict__ candVal, int* __restrict__ candIdx,
                        int* __restrict__ candCount, int* __restrict__ counts2d) {
    __shared__ int lcnt[C];
    int t = threadIdx.x;
    if (t < C) lcnt[t] = 0;
    __syncthreads();
    int gid = blockIdx.x * 256 + t;
    int b = gid / HW, p = gid % HW;
    int h = p / W, w = p % W;
    const float* s = sem2in + (size_t)b * C * HW + p;
    float best = s[0]; int cls = 0;
#pragma unroll
    for (int c = 1; c < C; ++c) {
        float v = s[(size_t)c * HW];
        if (v > best) { best = v; cls = c; }
    }
    semMap[gid] = (uint8_t)cls;
    atomicAdd(&lcnt[cls], 1);
    // heatmap NMS: local max under 7x7 window (SAME padding == clamped window)
    const float* hmb = center2d + (size_t)b * HW;
    float hm = hmb[p];
    float m = -INFINITY;
    int h0 = max(h - NMSR, 0), h1 = min(h + NMSR, H - 1);
    int w0 = max(w - NMSR, 0), w1 = min(w + NMSR, W - 1);
    for (int y = h0; y <= h1; ++y)
        for (int x = w0; x <= w1; ++x)
            m = fmaxf(m, hmb[y * W + x]);
    bool cand = (hm == m);
    nmsMask[gid] = cand ? 1 : 0;
    if (cand) {
        int pos = atomicAdd(&candCount[b], 1);
        if (pos < HW) {
            candVal[(size_t)b * HW + pos] = hm;
            candIdx[(size_t)b * HW + pos] = p;
        }
    }
    __syncthreads();
    if (t < C) atomicAdd(&counts2d[b * C + t], lcnt[t]);
}

// rank-based exact top-k: matches lax.top_k (desc values, lower index first on ties)
__global__ void k_topk(const uint8_t* __restrict__ semMap, const uint8_t* __restrict__ nmsMask,
                       const float* __restrict__ candVal, const int* __restrict__ candIdx,
                       const int* __restrict__ candCount,
                       float* __restrict__ cyA, float* __restrict__ cxA,
                       float* __restrict__ scA, int* __restrict__ clA) {
    int b = blockIdx.x >> 5;
    int sub = blockIdx.x & 31;
    int t = threadIdx.x;
    int n = candCount[b];
    if (n > HW) n = HW;
    const float* cv = candVal + (size_t)b * HW;
    const int*  ci = candIdx + (size_t)b * HW;
    for (int i = sub * 256 + t; i < n; i += 32 * 256) {
        float v = cv[i]; int id = ci[i];
        int rank = 0;
        for (int j = 0; j < n; ++j) {
            float vj = cv[j]; int ij = ci[j];
            rank += (vj > v) || (vj == v && ij < id);
        }
        if (rank < K) {
            int o = b * K + rank;
            cyA[o] = (float)(id / W);
            cxA[o] = (float)(id % W);
            scA[o] = v;
            clA[o] = (int)semMap[(size_t)b * HW + id];
        }
    }
    // rare path: fewer than K candidates -> zeros at first non-candidate indices
    if (sub == 0 && t == 0 && n < K) {
        int r = n;
        for (int p = 0; p < HW && r < K; ++p) {
            if (!nmsMask[(size_t)b * HW + p]) {
                int o = b * K + r;
                cyA[o] = (float)(p / W);
                cxA[o] = (float)(p % W);
                scA[o] = 0.0f;
                clA[o] = (int)semMap[(size_t)b * HW + p];
                ++r;
            }
        }
    }
}

__global__ void k_wrctr(const float* __restrict__ cyA, const float* __restrict__ cxA,
                        const float* __restrict__ scA, const int* __restrict__ clA,
                        float* __restrict__ out) {
    int t = blockIdx.x * 256 + threadIdx.x;
    if (t < B * K) {
        out[O_CENT + (size_t)t * 2 + 0] = cyA[t];
        out[O_CENT + (size_t)t * 2 + 1] = cxA[t];
        out[O_CLS + t] = (float)clA[t];
        out[O_SCR + t] = scA[t];
    }
}

__global__ void k_pan2d(const float* __restrict__ offset2d,
                        const uint8_t* __restrict__ semMap,
                        const float* __restrict__ cyA, const float* __restrict__ cxA,
                        const float* __restrict__ scA, const int* __restrict__ clA,
                        const int* __restrict__ counts2d,
                        float* __restrict__ out) {
#pragma clang fp contract(off)
    __shared__ float cyL[K], cxL[K];
    __shared__ int clsL[K];
    __shared__ int cntL[C];
    __shared__ int anyV;
    int t = threadIdx.x;
    int gid = blockIdx.x * 256 + t;
    int b = gid / HW, p = gid % HW;
    if (t < K) {
        float sc = scA[b * K + t];
        bool val = sc > CENTER_THRESHOLD;
        cyL[t] = val ? cyA[b * K + t] : INFINITY;
        cxL[t] = val ? cxA[b * K + t] : INFINITY;
        clsL[t] = clA[b * K + t];
    }
    if (t < C) cntL[t] = counts2d[b * C + t];
    if (t == 0) anyV = (scA[b * K] > CENTER_THRESHOLD) ? 1 : 0;
    __syncthreads();
    int h = p / W, w = p % W;
    float py = (float)h + offset2d[(size_t)b * 2 * HW + p];
    float px = (float)w + offset2d[(size_t)b * 2 * HW + HW + p];
    float bestd = INFINITY; int inst = 0;
#pragma unroll 8
    for (int k = 0; k < K; ++k) {
        float dy = py - cyL[k];
        float dx = px - cxL[k];
        float d = dy * dy + dx * dx;
        if (d < bestd) { bestd = d; inst = k; }
    }
    int sem = (int)semMap[gid];
    int pan;
    if (sem >= 1 && sem <= 7) {
        pan = anyV ? (clsL[inst] * LABEL_DIVISOR + inst + 1) : 0;
    } else {
        pan = (cntL[sem] >= STUFF_AREA) ? sem * LABEL_DIVISOR : 0;
    }
    out[O_PAN2 + gid] = (float)pan;
}

__global__ void k_geom3d(const float* __restrict__ geom, const float* __restrict__ occ,
                         const float* __restrict__ sem3in,
                         uint8_t* __restrict__ sem3Map, int* __restrict__ counts3d,
                         float* __restrict__ out) {
    __shared__ int lcnt[C];
    int t = threadIdx.x;
    if (t < C) lcnt[t] = 0;
    __syncthreads();
    int gid = blockIdx.x * 256 + t;
    int b = gid / G3, v = gid % G3;
    float g = geom[gid];
    float o = occ[gid];
    float gout = (o <= 0.0f) ? TRUNCATION : g;
    out[O_GEOM + gid] = gout;
    bool fg = fabsf(gout) < TSDF_THRESH;
    const float* s = sem3in + (size_t)b * C * G3 + v;
    float best = s[0]; int cls = 0;
#pragma unroll
    for (int c = 1; c < C; ++c) {
        float x = s[(size_t)c * G3];
        if (x > best) { best = x; cls = c; }
    }
    sem3Map[gid] = (uint8_t)cls;
    if (fg) atomicAdd(&lcnt[cls], 1);
    __syncthreads();
    if (t < C) atomicAdd(&counts3d[b * C + t], lcnt[t]);
}

__global__ void k_pan3d(const float* __restrict__ off3,
                        const uint8_t* __restrict__ sem3Map,
                        const float* __restrict__ cyA, const float* __restrict__ cxA,
                        const float* __restrict__ scA, const int* __restrict__ clA,
                        const int* __restrict__ counts3d,
                        const float* __restrict__ intr,
                        const float* __restrict__ geomOut,
                        float* __restrict__ out) {
#pragma clang fp contract(off)
    __shared__ float cyL[K], cxL[K];
    __shared__ int clsL[K];
    __shared__ int cntL[C];
    __shared__ int anyV;
    __shared__ float fx, fy, u0, v0;
    int t = threadIdx.x;
    int gid = blockIdx.x * 256 + t;
    int b = gid / G3, v = gid % G3;
    if (t < K) {
        float sc = scA[b * K + t];
        bool val = sc > CENTER_THRESHOLD;
        cyL[t] = val ? cyA[b * K + t] : INFINITY;
        cxL[t] = val ? cxA[b * K + t] : INFINITY;
        clsL[t] = clA[b * K + t];
    }
    if (t < C) cntL[t] = counts3d[b * C + t];
    if (t == 0) {
        anyV = (scA[b * K] > CENTER_THRESHOLD) ? 1 : 0;
        fx = intr[(size_t)b * 9 + 0];
        fy = intr[(size_t)b * 9 + 4];
        u0 = intr[(size_t)b * 9 + 2];
        v0 = intr[(size_t)b * 9 + 5];
    }
    __syncthreads();
    int i = v / (G * G);
    int rem = v % (G * G);
    int j = rem / G;
    int k3 = rem % G;
    float o0 = off3[(size_t)b * 3 * G3 + v];
    float o1 = off3[(size_t)b * 3 * G3 + G3 + v];
    float o2 = off3[(size_t)b * 3 * G3 + 2 * (size_t)G3 + v];
    float Xm = ((float)i + o0 + 0.5f) * VOXEL_SIZE - HALF_EXT;
    float Ym = ((float)j + o1 + 0.5f) * VOXEL_SIZE - HALF_EXT;
    float Zr = 0.0f + ((float)k3 + o2 + 0.5f) * VOXEL_SIZE;
    float Zm = fminf(fmaxf(Zr, 0.1f), DEPTH_MAX);
    float u = fx * Xm / Zm + u0;
    float vv = fy * Ym / Zm + v0;
    float bestd = INFINITY; int inst = 0;
#pragma unroll 8
    for (int k = 0; k < K; ++k) {
        float dv = vv - cyL[k];
        float du = u - cxL[k];
        float d = dv * dv + du * du;
        if (d < bestd) { bestd = d; inst = k; }
    }
    int sem = (int)sem3Map[gid];
    bool fg = fabsf(geomOut[gid]) < TSDF_THRESH;
    int pan;
    if (sem >= 1 && sem <= 7) {
        pan = anyV ? (clsL[inst] * LABEL_DIVISOR + inst + 1) : 0;
    } else {
        pan = (cntL[sem] >= STUFF_AREA) ? sem * LABEL_DIVISOR : 0;
    }
    out[O_PAN3 + gid] = fg ? (float)pan : 0.0f;
}

extern "C" void kernel_launch(void* const* d_in, const int* in_sizes, int n_in,
                              void* d_out, int out_size, void* d_ws, size_t ws_size,
                              hipStream_t stream) {
    const float* semantic2d  = (const float*)d_in[0];
    const float* center2d    = (const float*)d_in[1];
    const float* offset2d    = (const float*)d_in[2];
    const float* geometry    = (const float*)d_in[3];
    const float* occupancy3d = (const float*)d_in[4];
    const float* semantic3d  = (const float*)d_in[5];
    const float* offset3d    = (const float*)d_in[6];
    const float* intrinsic   = (const float*)d_in[7];
    float* out = (float*)d_out;
    char* ws = (char*)d_ws;

    int* candCount = (int*)(ws + 0);      // [B]
    int* counts2d  = (int*)(ws + 16);     // [B*C]
    int* counts3d  = (int*)(ws + 112);    // [B*C]
    float* cyA = (float*)(ws + WS_CY);
    float* cxA = (float*)(ws + WS_CX);
    float* scA = (float*)(ws + WS_SC);
    int*   clA = (int*)(ws + WS_CL);
    uint8_t* semMap  = (uint8_t*)(ws + WS_SEM2);
    uint8_t* nmsMask = (uint8_t*)(ws + WS_NMS);
    float* candVal = (float*)(ws + WS_CV);
    int*   candIdx = (int*)(ws + WS_CI);
    uint8_t* sem3Map = (uint8_t*)(ws + WS_SEM3);

    hipMemsetAsync(d_ws, 0, 256, stream);

    k_pre2d<<<(B * HW) / 256, 256, 0, stream>>>(semantic2d, center2d, semMap, nmsMask,
                                                candVal, candIdx, candCount, counts2d);
    k_topk<<<B * 32, 256, 0, stream>>>(semMap, nmsMask, candVal, candIdx, candCount,
                                       cyA, cxA, scA, clA);
    k_wrctr<<<1, 256, 0, stream>>>(cyA, cxA, scA, clA, out);
    k_pan2d<<<(B * HW) / 256, 256, 0, stream>>>(offset2d, semMap, cyA, cxA, scA, clA,
                                                counts2d, out);
    k_geom3d<<<(B * G3) / 256, 256, 0, stream>>>(geometry, occupancy3d, semantic3d,
                                                 sem3Map, counts3d, out);
    k_pan3d<<<(B * G3) / 256, 256, 0, stream>>>(offset3d, sem3Map, cyA, cxA, scA, clA,
                                                counts3d, intrinsic, out + O_GEOM, out);
}

// Round 2
// 191.907 us; speedup vs baseline: 1.8763x; 1.8763x over previous
//
#include <hip/hip_runtime.h>
#include <stdint.h>

constexpr int B = 2, H = 256, W = 256, G = 96, C = 12, K = 128;
constexpr int HW = H * W;          // 65536
constexpr int G3 = G * G * G;      // 884736
constexpr float CENTER_THRESHOLD = 0.1f;
constexpr int STUFF_AREA = 2048;
constexpr int LABEL_DIVISOR = 1000;
constexpr float VOXEL_SIZE = 0.0625f;
constexpr float TRUNCATION = 3.0f;
constexpr float TSDF_THRESH = 1.5f;
constexpr float DEPTH_MAX = 6.0f;
constexpr float HALF_EXT = 3.0f;   // G*VOXEL_SIZE/2
constexpr int TOPK_CAP = 6144;     // LDS candidate capacity (48 KB)

// output layout (floats)
constexpr size_t O_PAN2 = 0;
constexpr size_t O_PAN3 = 131072;
constexpr size_t O_GEOM = 1900544;
constexpr size_t O_CENT = 3670016;
constexpr size_t O_CLS  = 3670528;
constexpr size_t O_SCR  = 3670784;

// ws layout (bytes)
constexpr size_t WS_CY   = 256;
constexpr size_t WS_CX   = 1280;
constexpr size_t WS_SC   = 2304;
constexpr size_t WS_CL   = 3328;
constexpr size_t WS_SEM2 = 4352;
constexpr size_t WS_NMS  = 135424;
constexpr size_t WS_CV   = 266496;
constexpr size_t WS_CI   = 790784;
constexpr size_t WS_SEM3 = 1315072;

// One block per image row: separable clamped-window 7x7 max (7 vertical loads
// + 7 horizontal LDS reads instead of 49 global reads per pixel).
__global__ void k_pre2d(const float* __restrict__ sem2in,
                        const float* __restrict__ center2d,
                        uint8_t* __restrict__ semMap, uint8_t* __restrict__ nmsMask,
                        float* __restrict__ candVal, int* __restrict__ candIdx,
                        int* __restrict__ candCount, int* __restrict__ counts2d) {
    __shared__ float vmax[W];
    __shared__ int lcnt[C];
    int t = threadIdx.x;               // w
    int rb = blockIdx.x;               // b*H + h
    int b = rb / H, h = rb % H;
    if (t < C) lcnt[t] = 0;
    const float* hmb = center2d + (size_t)b * HW;
    int h0 = max(h - 3, 0), h1 = min(h + 3, H - 1);
    float m = -INFINITY;
    for (int y = h0; y <= h1; ++y) m = fmaxf(m, hmb[y * W + t]);
    vmax[t] = m;
    __syncthreads();
    int w0 = max(t - 3, 0), w1 = min(t + 3, W - 1);
    float mm = -INFINITY;
    for (int x = w0; x <= w1; ++x) mm = fmaxf(mm, vmax[x]);
    int p = h * W + t;
    float hm = hmb[p];
    // semantic argmax (first max wins, matches jnp.argmax)
    const float* s = sem2in + (size_t)b * C * HW + p;
    float best = s[0]; int cls = 0;
#pragma unroll
    for (int c = 1; c < C; ++c) {
        float v = s[(size_t)c * HW];
        if (v > best) { best = v; cls = c; }
    }
    int gid = b * HW + p;
    semMap[gid] = (uint8_t)cls;
    atomicAdd(&lcnt[cls], 1);
    bool cand = (hm == mm);
    nmsMask[gid] = cand ? 1 : 0;
    if (cand) {
        int pos = atomicAdd(&candCount[b], 1);
        if (pos < HW) {
            candVal[(size_t)b * HW + pos] = hm;
            candIdx[(size_t)b * HW + pos] = p;
        }
    }
    __syncthreads();
    if (t < C) atomicAdd(&counts2d[b * C + t], lcnt[t]);
}

// One block (1024 thr) per batch. Candidates staged in LDS; exact rank-based
// top-k (== lax.top_k: desc value, lower index first on ties). Fused output
// writer for centers/classes/scores.
__global__ __launch_bounds__(1024)
void k_topk(const uint8_t* __restrict__ semMap, const uint8_t* __restrict__ nmsMask,
            const float* __restrict__ candVal, const int* __restrict__ candIdx,
            const int* __restrict__ candCount,
            float* __restrict__ cyA, float* __restrict__ cxA,
            float* __restrict__ scA, int* __restrict__ clA,
            float* __restrict__ out) {
    __shared__ float2 cd[TOPK_CAP];
    int b = blockIdx.x;
    int t = threadIdx.x;
    int n = candCount[b];
    if (n > HW) n = HW;
    const float* cv = candVal + (size_t)b * HW;
    const int*  ci = candIdx + (size_t)b * HW;
    bool useLds = (n <= TOPK_CAP);
    if (useLds) {
        for (int i = t; i < n; i += 1024)
            cd[i] = make_float2(cv[i], __int_as_float(ci[i]));
    }
    __syncthreads();
    for (int i = t; i < n; i += 1024) {
        float v; int id;
        if (useLds) { float2 c = cd[i]; v = c.x; id = __float_as_int(c.y); }
        else        { v = cv[i]; id = ci[i]; }
        int rank = 0;
        if (useLds) {
#pragma unroll 4
            for (int j = 0; j < n; ++j) {
                float2 c = cd[j];
                float vj = c.x; int ij = __float_as_int(c.y);
                rank += (vj > v) || (vj == v && ij < id);
            }
        } else {
            for (int j = 0; j < n; ++j) {
                float vj = cv[j]; int ij = ci[j];
                rank += (vj > v) || (vj == v && ij < id);
            }
        }
        if (rank < K) {
            int o = b * K + rank;
            cyA[o] = (float)(id / W);
            cxA[o] = (float)(id % W);
            scA[o] = v;
            clA[o] = (int)semMap[(size_t)b * HW + id];
        }
    }
    __syncthreads();
    // rare path: fewer than K candidates -> zeros at first non-candidate pixels
    if (t == 0 && n < K) {
        int r = n;
        for (int p = 0; p < HW && r < K; ++p) {
            if (!nmsMask[(size_t)b * HW + p]) {
                int o = b * K + r;
                cyA[o] = (float)(p / W);
                cxA[o] = (float)(p % W);
                scA[o] = 0.0f;
                clA[o] = (int)semMap[(size_t)b * HW + p];
                ++r;
            }
        }
    }
    __syncthreads();
    if (t < K) {
        int o = b * K + t;
        out[O_CENT + (size_t)o * 2 + 0] = cyA[o];
        out[O_CENT + (size_t)o * 2 + 1] = cxA[o];
        out[O_CLS + o] = (float)clA[o];
        out[O_SCR + o] = scA[o];
    }
}

// 4 pixels per thread (W%4==0 so same row h, consecutive w).
__global__ void k_pan2d(const float* __restrict__ offset2d,
                        const uint8_t* __restrict__ semMap,
                        const float* __restrict__ cyA, const float* __restrict__ cxA,
                        const float* __restrict__ scA, const int* __restrict__ clA,
                        const int* __restrict__ counts2d,
                        float* __restrict__ out) {
#pragma clang fp contract(off)
    __shared__ float2 cc[K];
    __shared__ int clsL[K];
    __shared__ int cntL[C];
    __shared__ int anyV;
    int t = threadIdx.x;
    int base = (blockIdx.x * 256 + t) * 4;
    int b = base / HW, p = base % HW;
    if (t < K) {
        float sc = scA[b * K + t];
        bool val = sc > CENTER_THRESHOLD;
        cc[t] = make_float2(val ? cyA[b * K + t] : INFINITY,
                            val ? cxA[b * K + t] : INFINITY);
        clsL[t] = clA[b * K + t];
    }
    if (t < C) cntL[t] = counts2d[b * C + t];
    if (t == 0) anyV = (scA[b * K] > CENTER_THRESHOLD) ? 1 : 0;
    __syncthreads();
    int h = p / W, w = p % W;
    const float* offb = offset2d + (size_t)b * 2 * HW + p;
    float4 oy = *(const float4*)offb;
    float4 ox = *(const float4*)(offb + HW);
    float oya[4] = {oy.x, oy.y, oy.z, oy.w};
    float oxa[4] = {ox.x, ox.y, ox.z, ox.w};
    float py[4], px[4];
#pragma unroll
    for (int q = 0; q < 4; ++q) {
        py[q] = (float)h + oya[q];
        px[q] = (float)(w + q) + oxa[q];
    }
    float bestd[4] = {INFINITY, INFINITY, INFINITY, INFINITY};
    int inst[4] = {0, 0, 0, 0};
#pragma unroll 4
    for (int k = 0; k < K; ++k) {
        float2 c = cc[k];
#pragma unroll
        for (int q = 0; q < 4; ++q) {
            float dy = py[q] - c.x;
            float dx = px[q] - c.y;
            float d = dy * dy + dx * dx;
            if (d < bestd[q]) { bestd[q] = d; inst[q] = k; }
        }
    }
    uchar4 s4 = *(const uchar4*)(semMap + base);
    int sa[4] = {s4.x, s4.y, s4.z, s4.w};
    float pout[4];
#pragma unroll
    for (int q = 0; q < 4; ++q) {
        int sem = sa[q];
        int pan;
        if (sem >= 1 && sem <= 7) {
            pan = anyV ? (clsL[inst[q]] * LABEL_DIVISOR + inst[q] + 1) : 0;
        } else {
            pan = (cntL[sem] >= STUFF_AREA) ? sem * LABEL_DIVISOR : 0;
        }
        pout[q] = (float)pan;
    }
    *(float4*)(out + O_PAN2 + base) = make_float4(pout[0], pout[1], pout[2], pout[3]);
}

// 4 voxels per thread, float4-vectorized (G3%4==0; 1024-elem blocks never
// cross a batch boundary since G3/1024 is integral... 884736/1024=864).
__global__ void k_geom3d(const float* __restrict__ geom, const float* __restrict__ occ,
                         const float* __restrict__ sem3in,
                         uint8_t* __restrict__ sem3Map, int* __restrict__ counts3d,
                         float* __restrict__ out) {
    __shared__ int lcnt[C];
    int t = threadIdx.x;
    if (t < C) lcnt[t] = 0;
    __syncthreads();
    int base = (blockIdx.x * 256 + t) * 4;
    int b = base / G3, v = base % G3;
    float4 g = *(const float4*)(geom + base);
    float4 o = *(const float4*)(occ + base);
    float4 go;
    go.x = (o.x <= 0.0f) ? TRUNCATION : g.x;
    go.y = (o.y <= 0.0f) ? TRUNCATION : g.y;
    go.z = (o.z <= 0.0f) ? TRUNCATION : g.z;
    go.w = (o.w <= 0.0f) ? TRUNCATION : g.w;
    *(float4*)(out + O_GEOM + base) = go;
    const float* s = sem3in + (size_t)b * C * G3 + v;
    float4 s0 = *(const float4*)s;
    float bv[4] = {s0.x, s0.y, s0.z, s0.w};
    int bc[4] = {0, 0, 0, 0};
#pragma unroll
    for (int c = 1; c < C; ++c) {
        float4 x = *(const float4*)(s + (size_t)c * G3);
        float xa[4] = {x.x, x.y, x.z, x.w};
#pragma unroll
        for (int q = 0; q < 4; ++q)
            if (xa[q] > bv[q]) { bv[q] = xa[q]; bc[q] = c; }
    }
    *(uchar4*)(sem3Map + base) =
        make_uchar4((uint8_t)bc[0], (uint8_t)bc[1], (uint8_t)bc[2], (uint8_t)bc[3]);
    float ga[4] = {go.x, go.y, go.z, go.w};
#pragma unroll
    for (int q = 0; q < 4; ++q)
        if (fabsf(ga[q]) < TSDF_THRESH) atomicAdd(&lcnt[bc[q]], 1);
    __syncthreads();
    if (t < C) atomicAdd(&counts3d[b * C + t], lcnt[t]);
}

__global__ void k_pan3d(const float* __restrict__ off3,
                        const uint8_t* __restrict__ sem3Map,
                        const float* __restrict__ cyA, const float* __restrict__ cxA,
                        const float* __restrict__ scA, const int* __restrict__ clA,
                        const int* __restrict__ counts3d,
                        const float* __restrict__ intr,
                        const float* __restrict__ geomOut,
                        float* __restrict__ out) {
#pragma clang fp contract(off)
    __shared__ float2 cc[K];
    __shared__ int clsL[K];
    __shared__ int cntL[C];
    __shared__ int anyV;
    __shared__ float fxS, fyS, u0S, v0S;
    int t = threadIdx.x;
    int base = (blockIdx.x * 256 + t) * 4;
    int b = base / G3, v = base % G3;
    if (t < K) {
        float sc = scA[b * K + t];
        bool val = sc > CENTER_THRESHOLD;
        cc[t] = make_float2(val ? cyA[b * K + t] : INFINITY,
                            val ? cxA[b * K + t] : INFINITY);
        clsL[t] = clA[b * K + t];
    }
    if (t < C) cntL[t] = counts3d[b * C + t];
    if (t == 0) {
        anyV = (scA[b * K] > CENTER_THRESHOLD) ? 1 : 0;
        fxS = intr[(size_t)b * 9 + 0];
        fyS = intr[(size_t)b * 9 + 4];
        u0S = intr[(size_t)b * 9 + 2];
        v0S = intr[(size_t)b * 9 + 5];
    }
    __syncthreads();
    int i = v / (G * G);
    int rem = v % (G * G);
    int j = rem / G;
    int k0 = rem % G;                 // k0..k0+3 within one row (G%4==0)
    const float* ob = off3 + (size_t)b * 3 * G3 + v;
    float4 o0 = *(const float4*)ob;
    float4 o1 = *(const float4*)(ob + G3);
    float4 o2 = *(const float4*)(ob + 2 * (size_t)G3);
    float oa0[4] = {o0.x, o0.y, o0.z, o0.w};
    float oa1[4] = {o1.x, o1.y, o1.z, o1.w};
    float oa2[4] = {o2.x, o2.y, o2.z, o2.w};
    float fx = fxS, fy = fyS, u0 = u0S, v0 = v0S;
    float uu[4], vv[4];
#pragma unroll
    for (int q = 0; q < 4; ++q) {
        float Xm = ((float)i + oa0[q] + 0.5f) * VOXEL_SIZE - HALF_EXT;
        float Ym = ((float)j + oa1[q] + 0.5f) * VOXEL_SIZE - HALF_EXT;
        float Zr = 0.0f + ((float)(k0 + q) + oa2[q] + 0.5f) * VOXEL_SIZE;
        float Zm = fminf(fmaxf(Zr, 0.1f), DEPTH_MAX);
        uu[q] = fx * Xm / Zm + u0;
        vv[q] = fy * Ym / Zm + v0;
    }
    float bestd[4] = {INFINITY, INFINITY, INFINITY, INFINITY};
    int inst[4] = {0, 0, 0, 0};
#pragma unroll 4
    for (int k = 0; k < K; ++k) {
        float2 c = cc[k];
#pragma unroll
        for (int q = 0; q < 4; ++q) {
            float dv = vv[q] - c.x;
            float du = uu[q] - c.y;
            float d = dv * dv + du * du;
            if (d < bestd[q]) { bestd[q] = d; inst[q] = k; }
        }
    }
    uchar4 s4 = *(const uchar4*)(sem3Map + base);
    int sa[4] = {s4.x, s4.y, s4.z, s4.w};
    float4 gg = *(const float4*)(geomOut + base);
    float ga[4] = {gg.x, gg.y, gg.z, gg.w};
    float pout[4];
#pragma unroll
    for (int q = 0; q < 4; ++q) {
        int sem = sa[q];
        int pan;
        if (sem >= 1 && sem <= 7) {
            pan = anyV ? (clsL[inst[q]] * LABEL_DIVISOR + inst[q] + 1) : 0;
        } else {
            pan = (cntL[sem] >= STUFF_AREA) ? sem * LABEL_DIVISOR : 0;
        }
        pout[q] = (fabsf(ga[q]) < TSDF_THRESH) ? (float)pan : 0.0f;
    }
    *(float4*)(out + O_PAN3 + base) = make_float4(pout[0], pout[1], pout[2], pout[3]);
}

extern "C" void kernel_launch(void* const* d_in, const int* in_sizes, int n_in,
                              void* d_out, int out_size, void* d_ws, size_t ws_size,
                              hipStream_t stream) {
    const float* semantic2d  = (const float*)d_in[0];
    const float* center2d    = (const float*)d_in[1];
    const float* offset2d    = (const float*)d_in[2];
    const float* geometry    = (const float*)d_in[3];
    const float* occupancy3d = (const float*)d_in[4];
    const float* semantic3d  = (const float*)d_in[5];
    const float* offset3d    = (const float*)d_in[6];
    const float* intrinsic   = (const float*)d_in[7];
    float* out = (float*)d_out;
    char* ws = (char*)d_ws;

    int* candCount = (int*)(ws + 0);      // [B]
    int* counts2d  = (int*)(ws + 16);     // [B*C]
    int* counts3d  = (int*)(ws + 112);    // [B*C]
    float* cyA = (float*)(ws + WS_CY);
    float* cxA = (float*)(ws + WS_CX);
    float* scA = (float*)(ws + WS_SC);
    int*   clA = (int*)(ws + WS_CL);
    uint8_t* semMap  = (uint8_t*)(ws + WS_SEM2);
    uint8_t* nmsMask = (uint8_t*)(ws + WS_NMS);
    float* candVal = (float*)(ws + WS_CV);
    int*   candIdx = (int*)(ws + WS_CI);
    uint8_t* sem3Map = (uint8_t*)(ws + WS_SEM3);

    hipMemsetAsync(d_ws, 0, 256, stream);

    k_pre2d<<<B * H, 256, 0, stream>>>(semantic2d, center2d, semMap, nmsMask,
                                       candVal, candIdx, candCount, counts2d);
    k_topk<<<B, 1024, 0, stream>>>(semMap, nmsMask, candVal, candIdx, candCount,
                                   cyA, cxA, scA, clA, out);
    k_pan2d<<<(B * HW) / 1024, 256, 0, stream>>>(offset2d, semMap, cyA, cxA, scA, clA,
                                                 counts2d, out);
    k_geom3d<<<(B * G3) / 1024, 256, 0, stream>>>(geometry, occupancy3d, semantic3d,
                                                  sem3Map, counts3d, out);
    k_pan3d<<<(B * G3) / 1024, 256, 0, stream>>>(offset3d, sem3Map, cyA, cxA, scA, clA,
                                                 counts3d, intrinsic, out + O_GEOM, out);
}

// Round 3
// 134.443 us; speedup vs baseline: 2.6782x; 1.4274x over previous
//
#include <hip/hip_runtime.h>
#include <stdint.h>

constexpr int B = 2, H = 256, W = 256, G = 96, C = 12, K = 128;
constexpr int HW = H * W;          // 65536
constexpr int G3 = G * G * G;      // 884736
constexpr float CENTER_THRESHOLD = 0.1f;
constexpr int STUFF_AREA = 2048;
constexpr int LABEL_DIVISOR = 1000;
constexpr float VOXEL_SIZE = 0.0625f;
constexpr float TRUNCATION = 3.0f;
constexpr float TSDF_THRESH = 1.5f;
constexpr float DEPTH_MAX = 6.0f;
constexpr float HALF_EXT = 3.0f;   // G*VOXEL_SIZE/2
constexpr int TOPK_CAP = 6144;     // LDS candidate capacity (48 KB)
constexpr int TOPK_NB = 64;        // blocks per batch for k_topk

// output layout (floats)
constexpr size_t O_PAN2 = 0;
constexpr size_t O_PAN3 = 131072;
constexpr size_t O_GEOM = 1900544;
constexpr size_t O_CENT = 3670016;
constexpr size_t O_CLS  = 3670528;
constexpr size_t O_SCR  = 3670784;

// ws layout (bytes)
constexpr size_t WS_CY   = 256;
constexpr size_t WS_CX   = 1280;
constexpr size_t WS_SC   = 2304;
constexpr size_t WS_CL   = 3328;
constexpr size_t WS_SEM2 = 4352;
constexpr size_t WS_NMS  = 135424;
constexpr size_t WS_CV   = 266496;
constexpr size_t WS_CI   = 790784;
constexpr size_t WS_SEM3 = 1315072;

// One block per image row: separable clamped-window 7x7 max.
__global__ void k_pre2d(const float* __restrict__ sem2in,
                        const float* __restrict__ center2d,
                        uint8_t* __restrict__ semMap, uint8_t* __restrict__ nmsMask,
                        float* __restrict__ candVal, int* __restrict__ candIdx,
                        int* __restrict__ candCount, int* __restrict__ counts2d) {
    __shared__ float vmax[W];
    __shared__ int lcnt[C];
    int t = threadIdx.x;               // w
    int rb = blockIdx.x;               // b*H + h
    int b = rb / H, h = rb % H;
    if (t < C) lcnt[t] = 0;
    const float* hmb = center2d + (size_t)b * HW;
    int h0 = max(h - 3, 0), h1 = min(h + 3, H - 1);
    float m = -INFINITY;
    for (int y = h0; y <= h1; ++y) m = fmaxf(m, hmb[y * W + t]);
    vmax[t] = m;
    __syncthreads();
    int w0 = max(t - 3, 0), w1 = min(t + 3, W - 1);
    float mm = -INFINITY;
    for (int x = w0; x <= w1; ++x) mm = fmaxf(mm, vmax[x]);
    int p = h * W + t;
    float hm = hmb[p];
    // semantic argmax (first max wins, matches jnp.argmax)
    const float* s = sem2in + (size_t)b * C * HW + p;
    float best = s[0]; int cls = 0;
#pragma unroll
    for (int c = 1; c < C; ++c) {
        float v = s[(size_t)c * HW];
        if (v > best) { best = v; cls = c; }
    }
    int gid = b * HW + p;
    semMap[gid] = (uint8_t)cls;
    atomicAdd(&lcnt[cls], 1);
    bool cand = (hm == mm);
    nmsMask[gid] = cand ? 1 : 0;
    if (cand) {
        int pos = atomicAdd(&candCount[b], 1);
        if (pos < HW) {
            candVal[(size_t)b * HW + pos] = hm;
            candIdx[(size_t)b * HW + pos] = p;
        }
    }
    __syncthreads();
    if (t < C) atomicAdd(&counts2d[b * C + t], lcnt[t]);
}

// Wave-per-candidate exact top-k. Rank scan split across the 64 lanes
// (stride-64 LDS reads, conflict-free) + shfl_xor sum. Rank scatter is
// order-invariant (matches lax.top_k: desc value, lower index on ties).
// Winning lane writes both ws arrays and the final out[] entries.
__global__ __launch_bounds__(256)
void k_topk(const uint8_t* __restrict__ semMap, const uint8_t* __restrict__ nmsMask,
            const float* __restrict__ candVal, const int* __restrict__ candIdx,
            const int* __restrict__ candCount,
            float* __restrict__ cyA, float* __restrict__ cxA,
            float* __restrict__ scA, int* __restrict__ clA,
            float* __restrict__ out) {
    __shared__ float2 cd[TOPK_CAP];
    int b = blockIdx.x / TOPK_NB;
    int sub = blockIdx.x % TOPK_NB;
    int t = threadIdx.x;
    int lane = t & 63;
    int wv = sub * 4 + (t >> 6);       // wave index within batch [0, TOPK_NB*4)
    int n = candCount[b];
    if (n > HW) n = HW;
    const float* cv = candVal + (size_t)b * HW;
    const int*  ci = candIdx + (size_t)b * HW;
    bool useLds = (n <= TOPK_CAP);
    if (useLds) {
        for (int i = t; i < n; i += 256)
            cd[i] = make_float2(cv[i], __int_as_float(ci[i]));
    }
    __syncthreads();
    for (int i = wv; i < n; i += TOPK_NB * 4) {
        float v; int id;
        if (useLds) { float2 c = cd[i]; v = c.x; id = __float_as_int(c.y); }
        else        { v = cv[i]; id = ci[i]; }
        int r = 0;
        if (useLds) {
            for (int j = lane; j < n; j += 64) {
                float2 c = cd[j];
                r += (c.x > v) || (c.x == v && __float_as_int(c.y) < id);
            }
        } else {
            for (int j = lane; j < n; j += 64) {
                float vj = cv[j]; int ij = ci[j];
                r += (vj > v) || (vj == v && ij < id);
            }
        }
#pragma unroll
        for (int off = 32; off >= 1; off >>= 1) r += __shfl_xor(r, off, 64);
        if (lane == 0 && r < K) {
            int o = b * K + r;
            float fy = (float)(id / W);
            float fx = (float)(id % W);
            int cls = (int)semMap[(size_t)b * HW + id];
            cyA[o] = fy; cxA[o] = fx; scA[o] = v; clA[o] = cls;
            out[O_CENT + (size_t)o * 2 + 0] = fy;
            out[O_CENT + (size_t)o * 2 + 1] = fx;
            out[O_CLS + o] = (float)cls;
            out[O_SCR + o] = v;
        }
    }
    // rare path: fewer than K candidates -> zeros at first non-candidate pixels
    if (sub == 0 && t == 0 && n < K) {
        int r = n;
        for (int p = 0; p < HW && r < K; ++p) {
            if (!nmsMask[(size_t)b * HW + p]) {
                int o = b * K + r;
                float fy = (float)(p / W);
                float fx = (float)(p % W);
                int cls = (int)semMap[(size_t)b * HW + p];
                cyA[o] = fy; cxA[o] = fx; scA[o] = 0.0f; clA[o] = cls;
                out[O_CENT + (size_t)o * 2 + 0] = fy;
                out[O_CENT + (size_t)o * 2 + 1] = fx;
                out[O_CLS + o] = (float)cls;
                out[O_SCR + o] = 0.0f;
                ++r;
            }
        }
    }
}

// 4 pixels per thread (W%4==0 so same row h, consecutive w).
__global__ void k_pan2d(const float* __restrict__ offset2d,
                        const uint8_t* __restrict__ semMap,
                        const float* __restrict__ cyA, const float* __restrict__ cxA,
                        const float* __restrict__ scA, const int* __restrict__ clA,
                        const int* __restrict__ counts2d,
                        float* __restrict__ out) {
#pragma clang fp contract(off)
    __shared__ float2 cc[K];
    __shared__ int clsL[K];
    __shared__ int cntL[C];
    __shared__ int anyV;
    int t = threadIdx.x;
    int base = (blockIdx.x * 256 + t) * 4;
    int b = base / HW, p = base % HW;
    if (t < K) {
        float sc = scA[b * K + t];
        bool val = sc > CENTER_THRESHOLD;
        cc[t] = make_float2(val ? cyA[b * K + t] : INFINITY,
                            val ? cxA[b * K + t] : INFINITY);
        clsL[t] = clA[b * K + t];
    }
    if (t < C) cntL[t] = counts2d[b * C + t];
    if (t == 0) anyV = (scA[b * K] > CENTER_THRESHOLD) ? 1 : 0;
    __syncthreads();
    int h = p / W, w = p % W;
    const float* offb = offset2d + (size_t)b * 2 * HW + p;
    float4 oy = *(const float4*)offb;
    float4 ox = *(const float4*)(offb + HW);
    float oya[4] = {oy.x, oy.y, oy.z, oy.w};
    float oxa[4] = {ox.x, ox.y, ox.z, ox.w};
    float py[4], px[4];
#pragma unroll
    for (int q = 0; q < 4; ++q) {
        py[q] = (float)h + oya[q];
        px[q] = (float)(w + q) + oxa[q];
    }
    float bestd[4] = {INFINITY, INFINITY, INFINITY, INFINITY};
    int inst[4] = {0, 0, 0, 0};
#pragma unroll 4
    for (int k = 0; k < K; ++k) {
        float2 c = cc[k];
#pragma unroll
        for (int q = 0; q < 4; ++q) {
            float dy = py[q] - c.x;
            float dx = px[q] - c.y;
            float d = dy * dy + dx * dx;
            if (d < bestd[q]) { bestd[q] = d; inst[q] = k; }
        }
    }
    uchar4 s4 = *(const uchar4*)(semMap + base);
    int sa[4] = {s4.x, s4.y, s4.z, s4.w};
    float pout[4];
#pragma unroll
    for (int q = 0; q < 4; ++q) {
        int sem = sa[q];
        int pan;
        if (sem >= 1 && sem <= 7) {
            pan = anyV ? (clsL[inst[q]] * LABEL_DIVISOR + inst[q] + 1) : 0;
        } else {
            pan = (cntL[sem] >= STUFF_AREA) ? sem * LABEL_DIVISOR : 0;
        }
        pout[q] = (float)pan;
    }
    *(float4*)(out + O_PAN2 + base) = make_float4(pout[0], pout[1], pout[2], pout[3]);
}

// 4 voxels per thread, float4-vectorized.
__global__ void k_geom3d(const float* __restrict__ geom, const float* __restrict__ occ,
                         const float* __restrict__ sem3in,
                         uint8_t* __restrict__ sem3Map, int* __restrict__ counts3d,
                         float* __restrict__ out) {
    __shared__ int lcnt[C];
    int t = threadIdx.x;
    if (t < C) lcnt[t] = 0;
    __syncthreads();
    int base = (blockIdx.x * 256 + t) * 4;
    int b = base / G3, v = base % G3;
    float4 g = *(const float4*)(geom + base);
    float4 o = *(const float4*)(occ + base);
    float4 go;
    go.x = (o.x <= 0.0f) ? TRUNCATION : g.x;
    go.y = (o.y <= 0.0f) ? TRUNCATION : g.y;
    go.z = (o.z <= 0.0f) ? TRUNCATION : g.z;
    go.w = (o.w <= 0.0f) ? TRUNCATION : g.w;
    *(float4*)(out + O_GEOM + base) = go;
    const float* s = sem3in + (size_t)b * C * G3 + v;
    float4 s0 = *(const float4*)s;
    float bv[4] = {s0.x, s0.y, s0.z, s0.w};
    int bc[4] = {0, 0, 0, 0};
#pragma unroll
    for (int c = 1; c < C; ++c) {
        float4 x = *(const float4*)(s + (size_t)c * G3);
        float xa[4] = {x.x, x.y, x.z, x.w};
#pragma unroll
        for (int q = 0; q < 4; ++q)
            if (xa[q] > bv[q]) { bv[q] = xa[q]; bc[q] = c; }
    }
    *(uchar4*)(sem3Map + base) =
        make_uchar4((uint8_t)bc[0], (uint8_t)bc[1], (uint8_t)bc[2], (uint8_t)bc[3]);
    float ga[4] = {go.x, go.y, go.z, go.w};
#pragma unroll
    for (int q = 0; q < 4; ++q)
        if (fabsf(ga[q]) < TSDF_THRESH) atomicAdd(&lcnt[bc[q]], 1);
    __syncthreads();
    if (t < C) atomicAdd(&counts3d[b * C + t], lcnt[t]);
}

__global__ void k_pan3d(const float* __restrict__ off3,
                        const uint8_t* __restrict__ sem3Map,
                        const float* __restrict__ cyA, const float* __restrict__ cxA,
                        const float* __restrict__ scA, const int* __restrict__ clA,
                        const int* __restrict__ counts3d,
                        const float* __restrict__ intr,
                        const float* __restrict__ geomOut,
                        float* __restrict__ out) {
#pragma clang fp contract(off)
    __shared__ float2 cc[K];
    __shared__ int clsL[K];
    __shared__ int cntL[C];
    __shared__ int anyV;
    __shared__ float fxS, fyS, u0S, v0S;
    int t = threadIdx.x;
    int base = (blockIdx.x * 256 + t) * 4;
    int b = base / G3, v = base % G3;
    if (t < K) {
        float sc = scA[b * K + t];
        bool val = sc > CENTER_THRESHOLD;
        cc[t] = make_float2(val ? cyA[b * K + t] : INFINITY,
                            val ? cxA[b * K + t] : INFINITY);
        clsL[t] = clA[b * K + t];
    }
    if (t < C) cntL[t] = counts3d[b * C + t];
    if (t == 0) {
        anyV = (scA[b * K] > CENTER_THRESHOLD) ? 1 : 0;
        fxS = intr[(size_t)b * 9 + 0];
        fyS = intr[(size_t)b * 9 + 4];
        u0S = intr[(size_t)b * 9 + 2];
        v0S = intr[(size_t)b * 9 + 5];
    }
    __syncthreads();
    int i = v / (G * G);
    int rem = v % (G * G);
    int j = rem / G;
    int k0 = rem % G;                 // k0..k0+3 within one row (G%4==0)
    const float* ob = off3 + (size_t)b * 3 * G3 + v;
    float4 o0 = *(const float4*)ob;
    float4 o1 = *(const float4*)(ob + G3);
    float4 o2 = *(const float4*)(ob + 2 * (size_t)G3);
    float oa0[4] = {o0.x, o0.y, o0.z, o0.w};
    float oa1[4] = {o1.x, o1.y, o1.z, o1.w};
    float oa2[4] = {o2.x, o2.y, o2.z, o2.w};
    float fx = fxS, fy = fyS, u0 = u0S, v0 = v0S;
    float uu[4], vv[4];
#pragma unroll
    for (int q = 0; q < 4; ++q) {
        float Xm = ((float)i + oa0[q] + 0.5f) * VOXEL_SIZE - HALF_EXT;
        float Ym = ((float)j + oa1[q] + 0.5f) * VOXEL_SIZE - HALF_EXT;
        float Zr = 0.0f + ((float)(k0 + q) + oa2[q] + 0.5f) * VOXEL_SIZE;
        float Zm = fminf(fmaxf(Zr, 0.1f), DEPTH_MAX);
        uu[q] = fx * Xm / Zm + u0;
        vv[q] = fy * Ym / Zm + v0;
    }
    float bestd[4] = {INFINITY, INFINITY, INFINITY, INFINITY};
    int inst[4] = {0, 0, 0, 0};
#pragma unroll 4
    for (int k = 0; k < K; ++k) {
        float2 c = cc[k];
#pragma unroll
        for (int q = 0; q < 4; ++q) {
            float dv = vv[q] - c.x;
            float du = uu[q] - c.y;
            float d = dv * dv + du * du;
            if (d < bestd[q]) { bestd[q] = d; inst[q] = k; }
        }
    }
    uchar4 s4 = *(const uchar4*)(sem3Map + base);
    int sa[4] = {s4.x, s4.y, s4.z, s4.w};
    float4 gg = *(const float4*)(geomOut + base);
    float ga[4] = {gg.x, gg.y, gg.z, gg.w};
    float pout[4];
#pragma unroll
    for (int q = 0; q < 4; ++q) {
        int sem = sa[q];
        int pan;
        if (sem >= 1 && sem <= 7) {
            pan = anyV ? (clsL[inst[q]] * LABEL_DIVISOR + inst[q] + 1) : 0;
        } else {
            pan = (cntL[sem] >= STUFF_AREA) ? sem * LABEL_DIVISOR : 0;
        }
        pout[q] = (fabsf(ga[q]) < TSDF_THRESH) ? (float)pan : 0.0f;
    }
    *(float4*)(out + O_PAN3 + base) = make_float4(pout[0], pout[1], pout[2], pout[3]);
}

extern "C" void kernel_launch(void* const* d_in, const int* in_sizes, int n_in,
                              void* d_out, int out_size, void* d_ws, size_t ws_size,
                              hipStream_t stream) {
    const float* semantic2d  = (const float*)d_in[0];
    const float* center2d    = (const float*)d_in[1];
    const float* offset2d    = (const float*)d_in[2];
    const float* geometry    = (const float*)d_in[3];
    const float* occupancy3d = (const float*)d_in[4];
    const float* semantic3d  = (const float*)d_in[5];
    const float* offset3d    = (const float*)d_in[6];
    const float* intrinsic   = (const float*)d_in[7];
    float* out = (float*)d_out;
    char* ws = (char*)d_ws;

    int* candCount = (int*)(ws + 0);      // [B]
    int* counts2d  = (int*)(ws + 16);     // [B*C]
    int* counts3d  = (int*)(ws + 112);    // [B*C]
    float* cyA = (float*)(ws + WS_CY);
    float* cxA = (float*)(ws + WS_CX);
    float* scA = (float*)(ws + WS_SC);
    int*   clA = (int*)(ws + WS_CL);
    uint8_t* semMap  = (uint8_t*)(ws + WS_SEM2);
    uint8_t* nmsMask = (uint8_t*)(ws + WS_NMS);
    float* candVal = (float*)(ws + WS_CV);
    int*   candIdx = (int*)(ws + WS_CI);
    uint8_t* sem3Map = (uint8_t*)(ws + WS_SEM3);

    hipMemsetAsync(d_ws, 0, 256, stream);

    k_pre2d<<<B * H, 256, 0, stream>>>(semantic2d, center2d, semMap, nmsMask,
                                       candVal, candIdx, candCount, counts2d);
    k_topk<<<B * TOPK_NB, 256, 0, stream>>>(semMap, nmsMask, candVal, candIdx, candCount,
                                            cyA, cxA, scA, clA, out);
    k_pan2d<<<(B * HW) / 1024, 256, 0, stream>>>(offset2d, semMap, cyA, cxA, scA, clA,
                                                 counts2d, out);
    k_geom3d<<<(B * G3) / 1024, 256, 0, stream>>>(geometry, occupancy3d, semantic3d,
                                                  sem3Map, counts3d, out);
    k_pan3d<<<(B * G3) / 1024, 256, 0, stream>>>(offset3d, sem3Map, cyA, cxA, scA, clA,
                                                 counts3d, intrinsic, out + O_GEOM, out);
}